// Round 2
// baseline (177.688 us; speedup 1.0000x reference)
//
#include <hip/hip_runtime.h>
#include <hip/hip_bf16.h>

// Problem constants (fixed by the reference setup)
#define N_ROWS   500000
#define NR1      25        // nr + 1
#define NGROUPS  20000     // N_ROWS / NR1
#define KCTX     20        // K context indices
#define H        128
#define NODES    10000
#define IDX_COLS 23        // 3 + K

#define RPB      128       // rows per k_main block
#define MAXG     7         // max ctx groups spanned by 128 rows

typedef __attribute__((ext_vector_type(8))) short short8;   // 8 bf16 = 4 VGPRs
typedef __attribute__((ext_vector_type(4))) float f32x4;    // MFMA C/D

// pack two floats -> two bf16 (RNE) as a 32-bit word
__device__ __forceinline__ unsigned pkbf(float lo, float hi) {
  __hip_bfloat162 h = __float22bfloat162_rn(make_float2(lo, hi));
  union { __hip_bfloat162 h; unsigned u; } c; c.h = h;
  return c.u;
}
__device__ __forceinline__ float bf2f(unsigned short u) {
  union { unsigned u; float f; } c; c.u = ((unsigned)u) << 16; return c.f;
}

// ---------------------------------------------------------------------------
// Kernel 0 (new): per-group context means of x -> gm bf16 [NGROUPS][H].
//  Exploits linearity: mean(x[set]) @ W13.T == mean(x[set] @ W13.T), so the
//  ctx path needs only the mean embedding, projected once per group in
//  k_precompute (P3 table is dead; k_main's ctx phase is dead).
//  2500 blocks = 9.8 waves/SIMD: gather-latency tolerant.
// ---------------------------------------------------------------------------
#define GPB 8
#define MEAN_BLOCKS (NGROUPS / GPB)   // 2500
__global__ __launch_bounds__(256) void k_means(
    const int* __restrict__ indices, const float* __restrict__ x,
    unsigned short* __restrict__ gm) {
  const int tid = threadIdx.x;
  const int sub = tid >> 6;          // wave id: group selector
  const int jj  = (tid & 63) * 2;    // 2 cols per lane
#pragma unroll
  for (int it = 0; it < GPB / 4; ++it) {
    const int g = blockIdx.x * GPB + it * 4 + sub;   // < NGROUPS by construction
    const int* __restrict__ rowidx =
        indices + (size_t)g * NR1 * IDX_COLS + 3;    // wave-uniform -> s_load
    float s0 = 0.f, s1 = 0.f;
    int cnt = 0;
#pragma unroll
    for (int c = 0; c < KCTX; ++c) {
      const int idx = rowidx[c];
      const float2 v = *(const float2*)(x + (size_t)idx * H + jj);
      s0 += v.x; s1 += v.y;
      cnt += (idx > 0) ? 1 : 0;
    }
    const float rn = 1.f / (float)((cnt > 1) ? cnt : 1);
    *(unsigned*)(gm + (size_t)g * H + jj) = pkbf(s0 * rn, s1 * rn);
  }
}

// ---------------------------------------------------------------------------
// Kernel A (v6): flattened-grid precompute, 1411 blocks (was 628).
//  blocks [0,314)      : P1 = x @ W10.T   (157 tbase x 2 ct-halves)
//  blocks [314,628)    : P2 = x @ W11.T
//  blocks [628,1254)   : Pg = gm @ W13.T + b1  (f32, 313 tbase x 2 halves)
//  blocks [1254,1411)  : idx2 pack
//  ct-halving: each block stages only 64x128 of W1m (17.4 KB LDS, half the
//  serial staging of v5) and does 16 MFMAs -> 2x blocks, same total traffic.
// ---------------------------------------------------------------------------
#define PN 64
#define PBLK  ((NODES + PN - 1) / PN)      // 157
#define GBLK  ((NGROUPS + PN - 1) / PN)    // 313
#define B_PG  (4 * PBLK)                   // 628
#define B_IDX (B_PG + 2 * GBLK)            // 1254
#define PRE_BLOCKS (B_IDX + PBLK)          // 1411

__global__ __launch_bounds__(256) void k_precompute(
    const float* __restrict__ x, const float* __restrict__ W1,
    const float* __restrict__ b1, const unsigned short* __restrict__ gm,
    const int* __restrict__ indices,
    unsigned short* __restrict__ Pb, float* __restrict__ Pg,
    int2* __restrict__ idx2) {
  const int tid = threadIdx.x;
  const int bid = blockIdx.x;

  if (bid >= B_IDX) {                      // idx2 pack path
    const int stride = PBLK * 256;
    for (int r = (bid - B_IDX) * 256 + tid; r < N_ROWS; r += stride) {
      idx2[r] = make_int2(indices[(size_t)r * IDX_COLS + 0],
                          indices[(size_t)r * IDX_COLS + 1]);
    }
    return;
  }

  __shared__ short wlds[64][136];          // bf16 W1m[ch-half][k]: 17.4 KB

  const bool isPg = (bid >= B_PG);
  int m, sub;
  if (isPg) { m = 2; sub = bid - B_PG; }
  else      { m = bid / (2 * PBLK); sub = bid - m * (2 * PBLK); }
  const int tbase = (sub >> 1) * PN;       // node/group tile base
  const int ch    = sub & 1;               // which 64-output half

  // ---- stage W1m rows [ch*64, ch*64+64) x 128 cols -> LDS bf16 ----
#pragma unroll
  for (int it = 0; it < 8; ++it) {
    const int f  = it * 256 + tid;         // 0..2047
    const int j  = f >> 5;                 // 0..63
    const int q4 = f & 31;                 // float4 index in row
    const float4 v =
        *(const float4*)(W1 + (size_t)(ch * 64 + j) * (3 * H) + m * H + q4 * 4);
    *(unsigned*)&wlds[j][q4 * 4]     = pkbf(v.x, v.y);
    *(unsigned*)&wlds[j][q4 * 4 + 2] = pkbf(v.z, v.w);
  }
  __syncthreads();

  const int lane = tid & 63;
  const int wv   = tid >> 6;
  const int col  = lane & 15;
  const int quad = lane >> 4;

  // ---- A fragments: x rows (packed) or gm rows (already bf16) ----
  short8 Af[4];
  if (isPg) {
    int g = tbase + wv * 16 + col;
    if (g > NGROUPS - 1) g = NGROUPS - 1;
    const short8* __restrict__ gr = (const short8*)(gm + (size_t)g * H);
#pragma unroll
    for (int kt = 0; kt < 4; ++kt) Af[kt] = gr[kt * 4 + quad];
  } else {
    int node = tbase + wv * 16 + col;
    if (node > NODES - 1) node = NODES - 1;
    const float4* __restrict__ xr = (const float4*)(x + (size_t)node * H);
#pragma unroll
    for (int kt = 0; kt < 4; ++kt) {
      const int f4 = kt * 8 + quad * 2;
      const float4 v0 = xr[f4], v1 = xr[f4 + 1];
      union { short8 v; unsigned u[4]; } pk;
      pk.u[0] = pkbf(v0.x, v0.y);
      pk.u[1] = pkbf(v0.z, v0.w);
      pk.u[2] = pkbf(v1.x, v1.y);
      pk.u[3] = pkbf(v1.z, v1.w);
      Af[kt] = pk.v;
    }
  }

  f32x4 acc[4];
#pragma unroll
  for (int ct = 0; ct < 4; ++ct) acc[ct] = (f32x4)(0.f);

#pragma unroll
  for (int kt = 0; kt < 4; ++kt) {
#pragma unroll
    for (int ct = 0; ct < 4; ++ct) {
      const short8 Bf = *(const short8*)&wlds[ct * 16 + col][kt * 32 + quad * 8];
      acc[ct] = __builtin_amdgcn_mfma_f32_16x16x32_bf16(Af[kt], Bf, acc[ct], 0, 0, 0);
    }
  }

  if (isPg) {
    float b1v[4];
#pragma unroll
    for (int ct = 0; ct < 4; ++ct) b1v[ct] = b1[ch * 64 + ct * 16 + col];
#pragma unroll
    for (int reg = 0; reg < 4; ++reg) {
      const int g = tbase + wv * 16 + quad * 4 + reg;
      if (g < NGROUPS) {
#pragma unroll
        for (int ct = 0; ct < 4; ++ct)
          Pg[(size_t)g * H + ch * 64 + ct * 16 + col] = acc[ct][reg] + b1v[ct];
      }
    }
  } else {
    unsigned short* __restrict__ Pm = Pb + (size_t)m * NODES * H;
#pragma unroll
    for (int reg = 0; reg < 4; ++reg) {
      const int n = tbase + wv * 16 + quad * 4 + reg;
      if (n < NODES) {
#pragma unroll
        for (int ct = 0; ct < 4; ++ct) {
          union { unsigned u; unsigned short s[2]; } c;
          c.u = pkbf(acc[ct][reg], 0.f);
          Pm[(size_t)n * H + ch * 64 + ct * 16 + col] = c.s[0];
        }
      }
    }
  }
}

// ---------------------------------------------------------------------------
// Kernel C (v13): main kernel, 128 rows/block, 3907 blocks.
//  Ctx phase is GONE (hoisted to k_means + Pg projection): phase 0b is now a
//  <=224-float4 straight copy of the <=7 b1-folded Pg rows into LDS.
//  Critical path: issue gathers -> stage W2 -> barrier -> A-build -> MFMA.
// ---------------------------------------------------------------------------
__global__ __launch_bounds__(256) void k_main(
    const int2* __restrict__ idx2,
    const unsigned short* __restrict__ P1b, const unsigned short* __restrict__ P2b,
    const float* __restrict__ Pg,
    const float* __restrict__ W2, const float* __restrict__ b2,
    const float* __restrict__ W3, const float* __restrict__ b3,
    float* __restrict__ out) {
  __shared__ short w2s[64][136];      // bf16 W2[n][k], padded: 17.4 KB
  __shared__ float cgs[MAXG][132];    // ctx rows (b1 folded), padded: 3.7 KB

  const int tid   = threadIdx.x;
  const int rbase = blockIdx.x * RPB;
  const int gbase = rbase / NR1;

  const int lane = tid & 63;
  const int wv   = tid >> 6;
  const int col  = lane & 15;
  const int quad = lane >> 4;

  // ---- phase -1: issue scattered P1/P2 gathers (in flight across phase 0) ----
  short8 ua[2][4], ub[2][4];
  int    gl[2];
  {
    const int R = rbase + wv * 32;
#pragma unroll
    for (int rt = 0; rt < 2; ++rt) {
      const int r  = R + rt * 16 + col;
      const int rc = (r < N_ROWS) ? r : (N_ROWS - 1);
      const int2 ii = idx2[rc];
      const short8* __restrict__ pa = (const short8*)(P1b + (size_t)ii.x * H);
      const short8* __restrict__ pb = (const short8*)(P2b + (size_t)ii.y * H);
#pragma unroll
      for (int kt = 0; kt < 4; ++kt) {
        ua[rt][kt] = pa[kt * 4 + quad];
        ub[rt][kt] = pb[kt * 4 + quad];
      }
      gl[rt] = rc / NR1 - gbase;
    }
  }

  // ---- phase 0a: W2 -> LDS bf16 (coalesced float2 reads, L2-resident) ----
  for (int idx = tid; idx < 64 * 64; idx += 256) {
    const int n  = idx >> 6;
    const int kp = idx & 63;
    const float2 w = *(const float2*)(W2 + (size_t)n * H + kp * 2);
    *(unsigned*)&w2s[n][kp * 2] = pkbf(w.x, w.y);
  }

  // ---- phase 0b: copy <=7 precomputed ctx rows (b1 folded) from Pg ----
  {
    int rlast = rbase + RPB - 1; if (rlast > N_ROWS - 1) rlast = N_ROWS - 1;
    const int G = rlast / NR1 - gbase + 1;          // <= 7
    const float* __restrict__ Pgrow = Pg + (size_t)gbase * H;
    for (int i = tid; i < G * 32; i += 256) {       // G*32 float4s, single pass
      const int g = i >> 5;
      const int c = (i & 31) * 4;
      *(float4*)&cgs[g][c] = *(const float4*)(Pgrow + (size_t)g * H + c);
    }
  }
  __syncthreads();

  // epilogue constants (L1-hot, load once)
  float b2v[4], w3v[4];
#pragma unroll
  for (int ct = 0; ct < 4; ++ct) {
    b2v[ct] = b2[ct * 16 + col];
    w3v[ct] = W3[ct * 16 + col];
  }
  const float bias3 = b3[0];

  // ---- A-build: relu(P1[i0] + P2[i1] + ctx) -> bf16 fragments ----
  short8 A[2][4];
#pragma unroll
  for (int rt = 0; rt < 2; ++rt) {
#pragma unroll
    for (int kt = 0; kt < 4; ++kt) {
      union { short8 v; unsigned short s[8]; } va, vb;
      va.v = ua[rt][kt];
      vb.v = ub[rt][kt];
      const float4 c0 = *(const float4*)&cgs[gl[rt]][kt * 32 + quad * 8];
      const float4 c1 = *(const float4*)&cgs[gl[rt]][kt * 32 + quad * 8 + 4];
      const float h0 = fmaxf(bf2f(va.s[0]) + bf2f(vb.s[0]) + c0.x, 0.f);
      const float h1 = fmaxf(bf2f(va.s[1]) + bf2f(vb.s[1]) + c0.y, 0.f);
      const float h2 = fmaxf(bf2f(va.s[2]) + bf2f(vb.s[2]) + c0.z, 0.f);
      const float h3 = fmaxf(bf2f(va.s[3]) + bf2f(vb.s[3]) + c0.w, 0.f);
      const float h4 = fmaxf(bf2f(va.s[4]) + bf2f(vb.s[4]) + c1.x, 0.f);
      const float h5 = fmaxf(bf2f(va.s[5]) + bf2f(vb.s[5]) + c1.y, 0.f);
      const float h6 = fmaxf(bf2f(va.s[6]) + bf2f(vb.s[6]) + c1.z, 0.f);
      const float h7 = fmaxf(bf2f(va.s[7]) + bf2f(vb.s[7]) + c1.w, 0.f);
      union { short8 v; unsigned u[4]; } pk;
      pk.u[0] = pkbf(h0, h1);
      pk.u[1] = pkbf(h2, h3);
      pk.u[2] = pkbf(h4, h5);
      pk.u[3] = pkbf(h6, h7);
      A[rt][kt] = pk.v;
    }
  }

  // ---- MFMA layer 2 + epilogue + store ----
  f32x4 acc[2][4];
#pragma unroll
  for (int rt = 0; rt < 2; ++rt)
#pragma unroll
    for (int ct = 0; ct < 4; ++ct) acc[rt][ct] = (f32x4)(0.f);
#pragma unroll
  for (int kt = 0; kt < 4; ++kt) {
#pragma unroll
    for (int ct = 0; ct < 4; ++ct) {
      const short8 Bf = *(const short8*)&w2s[ct * 16 + col][kt * 32 + quad * 8];
#pragma unroll
      for (int rt = 0; rt < 2; ++rt)
        acc[rt][ct] = __builtin_amdgcn_mfma_f32_16x16x32_bf16(
            A[rt][kt], Bf, acc[rt][ct], 0, 0, 0);
    }
  }

  const int Rt = rbase + wv * 32;
#pragma unroll
  for (int rt = 0; rt < 2; ++rt) {
#pragma unroll
    for (int reg = 0; reg < 4; ++reg) {
      float s = 0.f;
#pragma unroll
      for (int ct = 0; ct < 4; ++ct)
        s += fmaxf(acc[rt][ct][reg] + b2v[ct], 0.f) * w3v[ct];
      s += __shfl_xor(s, 1);
      s += __shfl_xor(s, 2);
      s += __shfl_xor(s, 4);
      s += __shfl_xor(s, 8);
      if (col == 0) {
        const int row = Rt + rt * 16 + quad * 4 + reg;   // C row = quad*4+reg
        if (row < N_ROWS) out[row] = s + bias3;
      }
    }
  }
}

// ---------------------------------------------------------------------------
extern "C" void kernel_launch(void* const* d_in, const int* in_sizes, int n_in,
                              void* d_out, int out_size, void* d_ws, size_t ws_size,
                              hipStream_t stream) {
  const int*   indices = (const int*)  d_in[0];
  // d_in[1] = nr (scalar, fixed at 24)
  const float* x  = (const float*)d_in[2];
  const float* W1 = (const float*)d_in[3];
  const float* b1 = (const float*)d_in[4];
  const float* W2 = (const float*)d_in[5];
  const float* b2 = (const float*)d_in[6];
  const float* W3 = (const float*)d_in[7];
  const float* b3 = (const float*)d_in[8];
  float* out = (float*)d_out;

  // Workspace: P1 | P2 (bf16, 5.12 MB) | gm (bf16, 5.12 MB) | Pg (f32, 10.24 MB)
  //            | idx2 (4 MB)  => 24.5 MB total
  unsigned short* Pb  = (unsigned short*)d_ws;
  unsigned short* P1b = Pb;
  unsigned short* P2b = Pb + (size_t)NODES * H;
  unsigned short* gm  = Pb + (size_t)2 * NODES * H;
  float* Pg   = (float*)(gm + (size_t)NGROUPS * H);
  int2*  idx2 = (int2*)(Pg + (size_t)NGROUPS * H);

  k_means<<<MEAN_BLOCKS, 256, 0, stream>>>(indices, x, gm);
  k_precompute<<<PRE_BLOCKS, 256, 0, stream>>>(x, W1, b1, gm, indices,
                                               Pb, Pg, idx2);
  k_main<<<(N_ROWS + RPB - 1) / RPB, 256, 0, stream>>>(idx2, P1b, P2b, Pg,
                                                       W2, b2, W3, b3, out);
}

// Round 3
// 168.542 us; speedup vs baseline: 1.0543x; 1.0543x over previous
//
#include <hip/hip_runtime.h>
#include <hip/hip_bf16.h>

// Problem constants (fixed by the reference setup)
#define N_ROWS   500000
#define NR1      25        // nr + 1
#define NGROUPS  20000     // N_ROWS / NR1
#define KCTX     20        // K context indices
#define H        128
#define NODES    10000
#define IDX_COLS 23        // 3 + K

#define RPB      256       // rows per k_main block (2 tiles of 128)
#define NT       2         // tiles per block (ping-pong pipeline)
#define MAXG     12        // max ctx groups spanned by 256 rows

typedef __attribute__((ext_vector_type(8))) short short8;   // 8 bf16 = 4 VGPRs
typedef __attribute__((ext_vector_type(4))) float f32x4;    // MFMA C/D

// pack two floats -> two bf16 (RNE) as a 32-bit word
__device__ __forceinline__ unsigned pkbf(float lo, float hi) {
  __hip_bfloat162 h = __float22bfloat162_rn(make_float2(lo, hi));
  union { __hip_bfloat162 h; unsigned u; } c; c.h = h;
  return c.u;
}
__device__ __forceinline__ float bf2f(unsigned short u) {
  union { unsigned u; float f; } c; c.u = ((unsigned)u) << 16; return c.f;
}

// ---------------------------------------------------------------------------
// Kernel 0: per-group context means of x -> gm bf16 [NGROUPS][H].
//  (linearity: mean(x[set]) @ W13.T == mean(x[set] @ W13.T))
// ---------------------------------------------------------------------------
#define GPB 8
#define MEAN_BLOCKS (NGROUPS / GPB)   // 2500
__global__ __launch_bounds__(256) void k_means(
    const int* __restrict__ indices, const float* __restrict__ x,
    unsigned short* __restrict__ gm) {
  const int tid = threadIdx.x;
  const int sub = tid >> 6;          // wave id: group selector
  const int jj  = (tid & 63) * 2;    // 2 cols per lane
#pragma unroll
  for (int it = 0; it < GPB / 4; ++it) {
    const int g = blockIdx.x * GPB + it * 4 + sub;
    const int* __restrict__ rowidx =
        indices + (size_t)g * NR1 * IDX_COLS + 3;    // wave-uniform -> s_load
    float s0 = 0.f, s1 = 0.f;
    int cnt = 0;
#pragma unroll
    for (int c = 0; c < KCTX; ++c) {
      const int idx = rowidx[c];
      const float2 v = *(const float2*)(x + (size_t)idx * H + jj);
      s0 += v.x; s1 += v.y;
      cnt += (idx > 0) ? 1 : 0;
    }
    const float rn = 1.f / (float)((cnt > 1) ? cnt : 1);
    *(unsigned*)(gm + (size_t)g * H + jj) = pkbf(s0 * rn, s1 * rn);
  }
}

// ---------------------------------------------------------------------------
// Kernel A (v7): flattened-grid precompute, 1411 blocks. v6 + XOR-swizzled
//  wlds (the [64][136] pad left an 8-way bank conflict on b128 B-frag reads;
//  swizzle chunk^=(row&7) makes lanes 0-7 span all 8 bank-groups).
//  blocks [0,314)      : P1 = x @ W10.T   (157 tbase x 2 ct-halves)
//  blocks [314,628)    : P2 = x @ W11.T
//  blocks [628,1254)   : Pg = gm @ W13.T + b1  (f32)
//  blocks [1254,1411)  : idx2 pack
// ---------------------------------------------------------------------------
#define PN 64
#define PBLK  ((NODES + PN - 1) / PN)      // 157
#define GBLK  ((NGROUPS + PN - 1) / PN)    // 313
#define B_PG  (4 * PBLK)                   // 628
#define B_IDX (B_PG + 2 * GBLK)            // 1254
#define PRE_BLOCKS (B_IDX + PBLK)          // 1411

__global__ __launch_bounds__(256) void k_precompute(
    const float* __restrict__ x, const float* __restrict__ W1,
    const float* __restrict__ b1, const unsigned short* __restrict__ gm,
    const int* __restrict__ indices,
    unsigned short* __restrict__ Pb, float* __restrict__ Pg,
    int2* __restrict__ idx2) {
  const int tid = threadIdx.x;
  const int bid = blockIdx.x;

  if (bid >= B_IDX) {                      // idx2 pack path
    const int stride = PBLK * 256;
    for (int r = (bid - B_IDX) * 256 + tid; r < N_ROWS; r += stride) {
      idx2[r] = make_int2(indices[(size_t)r * IDX_COLS + 0],
                          indices[(size_t)r * IDX_COLS + 1]);
    }
    return;
  }

  __shared__ __align__(16) short wlds[64 * 128];   // 16 KB, XOR-swizzled

  const bool isPg = (bid >= B_PG);
  int m, sub;
  if (isPg) { m = 2; sub = bid - B_PG; }
  else      { m = bid / (2 * PBLK); sub = bid - m * (2 * PBLK); }
  const int tbase = (sub >> 1) * PN;       // node/group tile base
  const int ch    = sub & 1;               // which 64-output half

  // ---- stage W1m rows [ch*64, ch*64+64) x 128 cols -> LDS bf16, swizzled ----
#pragma unroll
  for (int it = 0; it < 8; ++it) {
    const int f  = it * 256 + tid;         // 0..2047
    const int j  = f >> 5;                 // 0..63 : LDS row
    const int q4 = f & 31;                 // float4 index in source row
    const float4 v =
        *(const float4*)(W1 + (size_t)(ch * 64 + j) * (3 * H) + m * H + q4 * 4);
    const int sidx = j * 128 + (((q4 >> 1) ^ (j & 7)) << 3) + (q4 & 1) * 4;
    *(unsigned*)&wlds[sidx]     = pkbf(v.x, v.y);
    *(unsigned*)&wlds[sidx + 2] = pkbf(v.z, v.w);
  }
  __syncthreads();

  const int lane = tid & 63;
  const int wv   = tid >> 6;
  const int col  = lane & 15;
  const int quad = lane >> 4;

  // ---- A fragments: x rows (packed) or gm rows (already bf16) ----
  short8 Af[4];
  if (isPg) {
    int g = tbase + wv * 16 + col;
    if (g > NGROUPS - 1) g = NGROUPS - 1;
    const short8* __restrict__ gr = (const short8*)(gm + (size_t)g * H);
#pragma unroll
    for (int kt = 0; kt < 4; ++kt) Af[kt] = gr[kt * 4 + quad];
  } else {
    int node = tbase + wv * 16 + col;
    if (node > NODES - 1) node = NODES - 1;
    const float4* __restrict__ xr = (const float4*)(x + (size_t)node * H);
#pragma unroll
    for (int kt = 0; kt < 4; ++kt) {
      const int f4 = kt * 8 + quad * 2;
      const float4 v0 = xr[f4], v1 = xr[f4 + 1];
      union { short8 v; unsigned u[4]; } pk;
      pk.u[0] = pkbf(v0.x, v0.y);
      pk.u[1] = pkbf(v0.z, v0.w);
      pk.u[2] = pkbf(v1.x, v1.y);
      pk.u[3] = pkbf(v1.z, v1.w);
      Af[kt] = pk.v;
    }
  }

  f32x4 acc[4];
#pragma unroll
  for (int ct = 0; ct < 4; ++ct) acc[ct] = (f32x4)(0.f);

#pragma unroll
  for (int kt = 0; kt < 4; ++kt) {
#pragma unroll
    for (int ct = 0; ct < 4; ++ct) {
      const int brow = ct * 16 + col;
      const short8 Bf = *(const short8*)
          &wlds[brow * 128 + (((kt * 4 + quad) ^ (brow & 7)) << 3)];
      acc[ct] = __builtin_amdgcn_mfma_f32_16x16x32_bf16(Af[kt], Bf, acc[ct], 0, 0, 0);
    }
  }

  if (isPg) {
    float b1v[4];
#pragma unroll
    for (int ct = 0; ct < 4; ++ct) b1v[ct] = b1[ch * 64 + ct * 16 + col];
#pragma unroll
    for (int reg = 0; reg < 4; ++reg) {
      const int g = tbase + wv * 16 + quad * 4 + reg;
      if (g < NGROUPS) {
#pragma unroll
        for (int ct = 0; ct < 4; ++ct)
          Pg[(size_t)g * H + ch * 64 + ct * 16 + col] = acc[ct][reg] + b1v[ct];
      }
    }
  } else {
    unsigned short* __restrict__ Pm = Pb + (size_t)m * NODES * H;
#pragma unroll
    for (int reg = 0; reg < 4; ++reg) {
      const int n = tbase + wv * 16 + quad * 4 + reg;
      if (n < NODES) {
#pragma unroll
        for (int ct = 0; ct < 4; ++ct) {
          union { unsigned u; unsigned short s[2]; } c;
          c.u = pkbf(acc[ct][reg], 0.f);
          Pm[(size_t)n * H + ch * 64 + ct * 16 + col] = c.s[0];
        }
      }
    }
  }
}

// ---------------------------------------------------------------------------
// Kernel C (v14): 256 rows/block, 1954 blocks, 2-tile ping-pong pipeline.
//  - W2 staged ONCE per 256 rows (halves the 122 MB/dispatch L2 re-read and
//    the pre-barrier critical path of v13's 3907 blocks)
//  - w2s XOR-swizzled [64*128] (kills the 1.0M/dispatch 8-way bank conflict
//    of the padded [64][136] layout)
//  - idx2 for BOTH tiles loaded before the barrier; tile-1 P1/P2 gathers
//    issued right after the barrier so they fly under tile-0 A-build+MFMA
// ---------------------------------------------------------------------------
__global__ __launch_bounds__(256) void k_main(
    const int2* __restrict__ idx2,
    const unsigned short* __restrict__ P1b, const unsigned short* __restrict__ P2b,
    const float* __restrict__ Pg,
    const float* __restrict__ W2, const float* __restrict__ b2,
    const float* __restrict__ W3, const float* __restrict__ b3,
    float* __restrict__ out) {
  __shared__ __align__(16) short w2s[64 * 128];   // 16 KB, XOR-swizzled
  __shared__ float cgs[MAXG][128];                // ctx rows (b1 folded), 6 KB

  const int tid   = threadIdx.x;
  const int rbase = blockIdx.x * RPB;
  const int gbase = rbase / NR1;

  const int lane = tid & 63;
  const int wv   = tid >> 6;
  const int col  = lane & 15;
  const int quad = lane >> 4;

  // ---- phase -1: idx2 for both tiles; issue tile-0 gathers ----
  short8 ua[2][2][4], ub[2][2][4];
  int    gl[2][2];
  int2   ii1[2];
  {
    const int R0 = rbase + wv * 32;
    const int R1 = R0 + 128;
    int rc0[2], rc1[2];
#pragma unroll
    for (int rt = 0; rt < 2; ++rt) {
      int r0 = R0 + rt * 16 + col; rc0[rt] = (r0 < N_ROWS) ? r0 : (N_ROWS - 1);
      int r1 = R1 + rt * 16 + col; rc1[rt] = (r1 < N_ROWS) ? r1 : (N_ROWS - 1);
    }
    int2 ii0[2];
#pragma unroll
    for (int rt = 0; rt < 2; ++rt) { ii0[rt] = idx2[rc0[rt]]; ii1[rt] = idx2[rc1[rt]]; }
#pragma unroll
    for (int rt = 0; rt < 2; ++rt) {
      const short8* __restrict__ pa = (const short8*)(P1b + (size_t)ii0[rt].x * H);
      const short8* __restrict__ pb = (const short8*)(P2b + (size_t)ii0[rt].y * H);
#pragma unroll
      for (int kt = 0; kt < 4; ++kt) {
        ua[0][rt][kt] = pa[kt * 4 + quad];
        ub[0][rt][kt] = pb[kt * 4 + quad];
      }
      gl[0][rt] = rc0[rt] / NR1 - gbase;
      gl[1][rt] = rc1[rt] / NR1 - gbase;
    }
  }

  // ---- phase 0a: W2 -> LDS bf16, swizzled (issues under idx2 latency) ----
  for (int i = tid; i < 2048; i += 256) {
    const int n  = i >> 5;                 // LDS row (output unit n)
    const int q4 = i & 31;                 // float4 index in source row
    const float4 w = *(const float4*)(W2 + (size_t)n * H + q4 * 4);
    const int sidx = n * 128 + (((q4 >> 1) ^ (n & 7)) << 3) + (q4 & 1) * 4;
    *(unsigned*)&w2s[sidx]     = pkbf(w.x, w.y);
    *(unsigned*)&w2s[sidx + 2] = pkbf(w.z, w.w);
  }

  // ---- phase 0b: copy <=12 precomputed ctx rows (b1 folded) from Pg ----
  {
    int rlast = rbase + RPB - 1; if (rlast > N_ROWS - 1) rlast = N_ROWS - 1;
    const int G = rlast / NR1 - gbase + 1;          // <= 12
    const float* __restrict__ Pgrow = Pg + (size_t)gbase * H;
    for (int i = tid; i < G * 32; i += 256) {
      const int g = i >> 5;
      const int c = (i & 31) * 4;
      *(float4*)&cgs[g][c] = *(const float4*)(Pgrow + (size_t)g * H + c);
    }
  }
  __syncthreads();

  // epilogue constants (L1-hot, load once)
  float b2v[4], w3v[4];
#pragma unroll
  for (int ct = 0; ct < 4; ++ct) {
    b2v[ct] = b2[ct * 16 + col];
    w3v[ct] = W3[ct * 16 + col];
  }
  const float bias3 = b3[0];

#pragma unroll
  for (int t = 0; t < NT; ++t) {
    const int cur = t & 1;

    // ---- issue tile t+1 gathers (in flight under tile-t A-build + MFMA) ----
    if (t + 1 < NT) {
      const int nxt = cur ^ 1;
#pragma unroll
      for (int rt = 0; rt < 2; ++rt) {
        const short8* __restrict__ pa = (const short8*)(P1b + (size_t)ii1[rt].x * H);
        const short8* __restrict__ pb = (const short8*)(P2b + (size_t)ii1[rt].y * H);
#pragma unroll
        for (int kt = 0; kt < 4; ++kt) {
          ua[nxt][rt][kt] = pa[kt * 4 + quad];
          ub[nxt][rt][kt] = pb[kt * 4 + quad];
        }
      }
    }

    // ---- A-build: relu(P1[i0] + P2[i1] + ctx) -> bf16 fragments ----
    short8 A[2][4];
#pragma unroll
    for (int rt = 0; rt < 2; ++rt) {
#pragma unroll
      for (int kt = 0; kt < 4; ++kt) {
        union { short8 v; unsigned short s[8]; } va, vb;
        va.v = ua[cur][rt][kt];
        vb.v = ub[cur][rt][kt];
        const float4 c0 = *(const float4*)&cgs[gl[cur][rt]][kt * 32 + quad * 8];
        const float4 c1 = *(const float4*)&cgs[gl[cur][rt]][kt * 32 + quad * 8 + 4];
        const float h0 = fmaxf(bf2f(va.s[0]) + bf2f(vb.s[0]) + c0.x, 0.f);
        const float h1 = fmaxf(bf2f(va.s[1]) + bf2f(vb.s[1]) + c0.y, 0.f);
        const float h2 = fmaxf(bf2f(va.s[2]) + bf2f(vb.s[2]) + c0.z, 0.f);
        const float h3 = fmaxf(bf2f(va.s[3]) + bf2f(vb.s[3]) + c0.w, 0.f);
        const float h4 = fmaxf(bf2f(va.s[4]) + bf2f(vb.s[4]) + c1.x, 0.f);
        const float h5 = fmaxf(bf2f(va.s[5]) + bf2f(vb.s[5]) + c1.y, 0.f);
        const float h6 = fmaxf(bf2f(va.s[6]) + bf2f(vb.s[6]) + c1.z, 0.f);
        const float h7 = fmaxf(bf2f(va.s[7]) + bf2f(vb.s[7]) + c1.w, 0.f);
        union { short8 v; unsigned u[4]; } pk;
        pk.u[0] = pkbf(h0, h1);
        pk.u[1] = pkbf(h2, h3);
        pk.u[2] = pkbf(h4, h5);
        pk.u[3] = pkbf(h6, h7);
        A[rt][kt] = pk.v;
      }
    }

    // ---- MFMA layer 2 + epilogue + store for tile t ----
    f32x4 acc[2][4];
#pragma unroll
    for (int rt = 0; rt < 2; ++rt)
#pragma unroll
      for (int ct = 0; ct < 4; ++ct) acc[rt][ct] = (f32x4)(0.f);
#pragma unroll
    for (int kt = 0; kt < 4; ++kt) {
#pragma unroll
      for (int ct = 0; ct < 4; ++ct) {
        const int brow = ct * 16 + col;
        const short8 Bf = *(const short8*)
            &w2s[brow * 128 + (((kt * 4 + quad) ^ (brow & 7)) << 3)];
#pragma unroll
        for (int rt = 0; rt < 2; ++rt)
          acc[rt][ct] = __builtin_amdgcn_mfma_f32_16x16x32_bf16(
              A[rt][kt], Bf, acc[rt][ct], 0, 0, 0);
      }
    }

    const int Rt = rbase + t * 128 + wv * 32;
#pragma unroll
    for (int rt = 0; rt < 2; ++rt) {
#pragma unroll
      for (int reg = 0; reg < 4; ++reg) {
        float s = 0.f;
#pragma unroll
        for (int ct = 0; ct < 4; ++ct)
          s += fmaxf(acc[rt][ct][reg] + b2v[ct], 0.f) * w3v[ct];
        s += __shfl_xor(s, 1);
        s += __shfl_xor(s, 2);
        s += __shfl_xor(s, 4);
        s += __shfl_xor(s, 8);
        if (col == 0) {
          const int row = Rt + rt * 16 + quad * 4 + reg;   // C row = quad*4+reg
          if (row < N_ROWS) out[row] = s + bias3;
        }
      }
    }
  }
}

// ---------------------------------------------------------------------------
extern "C" void kernel_launch(void* const* d_in, const int* in_sizes, int n_in,
                              void* d_out, int out_size, void* d_ws, size_t ws_size,
                              hipStream_t stream) {
  const int*   indices = (const int*)  d_in[0];
  // d_in[1] = nr (scalar, fixed at 24)
  const float* x  = (const float*)d_in[2];
  const float* W1 = (const float*)d_in[3];
  const float* b1 = (const float*)d_in[4];
  const float* W2 = (const float*)d_in[5];
  const float* b2 = (const float*)d_in[6];
  const float* W3 = (const float*)d_in[7];
  const float* b3 = (const float*)d_in[8];
  float* out = (float*)d_out;

  // Workspace: P1 | P2 (bf16, 5.12 MB) | gm (bf16, 5.12 MB) | Pg (f32, 10.24 MB)
  //            | idx2 (4 MB)  => 24.5 MB total
  unsigned short* Pb  = (unsigned short*)d_ws;
  unsigned short* P1b = Pb;
  unsigned short* P2b = Pb + (size_t)NODES * H;
  unsigned short* gm  = Pb + (size_t)2 * NODES * H;
  float* Pg   = (float*)(gm + (size_t)NGROUPS * H);
  int2*  idx2 = (int2*)(Pg + (size_t)NGROUPS * H);

  k_means<<<MEAN_BLOCKS, 256, 0, stream>>>(indices, x, gm);
  k_precompute<<<PRE_BLOCKS, 256, 0, stream>>>(x, W1, b1, gm, indices,
                                               Pb, Pg, idx2);
  k_main<<<(N_ROWS + RPB - 1) / RPB, 256, 0, stream>>>(idx2, P1b, P2b, Pg,
                                                       W2, b2, W3, b3, out);
}